// Round 1
// 197.667 us; speedup vs baseline: 1.0095x; 1.0095x over previous
//
#include <hip/hip_runtime.h>
#include <math.h>

#define BATCH   2
#define T_SEQ   2048
#define DMODEL  1024
#define NHEAD   16
#define HDIM    64

typedef short s16x8 __attribute__((ext_vector_type(8)));
typedef unsigned short u16x8 __attribute__((ext_vector_type(8)));
typedef unsigned short u16x4 __attribute__((ext_vector_type(4)));
typedef unsigned int u32x2 __attribute__((ext_vector_type(2)));
typedef float f32x4 __attribute__((ext_vector_type(4)));

typedef const unsigned int __attribute__((address_space(1))) GUI;
typedef unsigned int __attribute__((address_space(3))) LUI;

// fp32 -> bf16 round-to-nearest-even (bit pattern)
static __device__ __forceinline__ unsigned short f2bf(float f) {
    unsigned int u = __float_as_uint(f);
    u += 0x7fffu + ((u >> 16) & 1u);
    return (unsigned short)(u >> 16);
}

// two fp32 -> packed bf16x2 (round-half-up) via one v_perm_b32
static __device__ __forceinline__ unsigned int f2bf_pack2(float a, float b) {
    const unsigned int ua = __float_as_uint(a) + 0x8000u;
    const unsigned int ub = __float_as_uint(b) + 0x8000u;
    return __builtin_amdgcn_perm(ub, ua, 0x07060302u);
}

// ---------------------------------------------------------------------------
// Fused prep: blocks 0..2047 convert x -> bf16; 2048..2815 transpose Wqkv;
// 2816..3071 transpose Wout; 3072..3327 build RoPE cos/sin table
// tab[t][d2] = (cos(t*f_d2), sin(t*f_d2)), f_d2 = 10000^(-d2/32).
// ---------------------------------------------------------------------------
__global__ __launch_bounds__(256) void prep_fused(
    const float* __restrict__ x, const float* __restrict__ Wqkv,
    const float* __restrict__ Wout,
    unsigned short* __restrict__ xb, unsigned short* __restrict__ Wqkv_t,
    unsigned short* __restrict__ Wout_t, float2* __restrict__ rope_tab)
{
    __shared__ unsigned short tile[64][68];
    const int bid = blockIdx.x;
    const int tid = threadIdx.x;

    if (bid < 2048) {
        const int i = bid * 256 + tid;
        const float4 a = ((const float4*)x)[2 * i];
        const float4 b = ((const float4*)x)[2 * i + 1];
        u16x8 r;
        r[0] = f2bf(a.x); r[1] = f2bf(a.y); r[2] = f2bf(a.z); r[3] = f2bf(a.w);
        r[4] = f2bf(b.x); r[5] = f2bf(b.y); r[6] = f2bf(b.z); r[7] = f2bf(b.w);
        ((u16x8*)xb)[i] = r;
        return;
    }
    if (bid >= 3072) {
        const int idx = (bid - 3072) * 256 + tid;
        const int t = idx >> 5;
        const int d2 = idx & 31;
        const float inv_freq = exp2f(-(float)d2 * 0.41524101186092029f); // log2(1e4)/32
        float s, c;
        sincosf((float)t * inv_freq, &s, &c);
        rope_tab[idx] = make_float2(c, s);
        return;
    }

    const float* src;
    unsigned short* dst;
    int R, C, bx, by;
    if (bid < 2816) {
        const int id = bid - 2048;
        src = Wqkv; dst = Wqkv_t; R = DMODEL; C = 3 * DMODEL;
        bx = id % 48; by = id / 48;
    } else {
        const int id = bid - 2816;
        src = Wout; dst = Wout_t; R = DMODEL; C = DMODEL;
        bx = id % 16; by = id / 16;
    }
    const int tc0 = bx * 64;
    const int tr0 = by * 64;
    const int tx = tid & 63;
    const int ty = tid >> 6;
#pragma unroll
    for (int i = 0; i < 16; i++) {
        const int rr = i * 4 + ty;
        tile[tx][rr] = f2bf(src[(size_t)(tr0 + rr) * C + tc0 + tx]);
    }
    __syncthreads();
#pragma unroll
    for (int i = 0; i < 16; i++) {
        const int cc = i * 4 + ty;
        dst[(size_t)(tc0 + cc) * R + tr0 + tx] = tile[cc][tx];
    }
}

// ---------------------------------------------------------------------------
// Shared MFMA GEMM main loop, DOUBLE-BUFFERED, one barrier per K-slice.
// (still used by gemm_out_mfma)
// ---------------------------------------------------------------------------
__device__ __forceinline__ void mfma_gemm_loop_db(
    const unsigned short* __restrict__ A, const unsigned short* __restrict__ Bt,
    unsigned short* As, unsigned short* Bs,
    int m0, int n0, int K, f32x4 acc[4][4])
{
    const int tid  = threadIdx.x;
    const int wave = tid >> 6;
    const int lane = tid & 63;
    const int quad = lane >> 4;
    const int lc   = lane & 15;
    const int wr   = (wave >> 1) * 64;
    const int wc   = (wave & 1) * 64;

    const int c0    = wave * 2;
    const int srow0 = c0 * 16 + (lane >> 2);
    const int scol  = (lane & 3) * 8;

#pragma unroll
    for (int i = 0; i < 4; i++)
#pragma unroll
        for (int j = 0; j < 4; j++)
            acc[i][j] = (f32x4){0.f, 0.f, 0.f, 0.f};

    auto stage = [&](int kt, int buf) {
        const unsigned short* ga0 = A + (size_t)(m0 + srow0) * K + kt + scol;
        const unsigned short* ga1 = A + (size_t)(m0 + srow0 + 16) * K + kt + scol;
        const unsigned short* gb0 = Bt + (size_t)(n0 + srow0) * K + kt + scol;
        const unsigned short* gb1 = Bt + (size_t)(n0 + srow0 + 16) * K + kt + scol;
        unsigned short* as = As + buf * 4096;
        unsigned short* bs = Bs + buf * 4096;
        __builtin_amdgcn_global_load_lds((GUI*)ga0, (LUI*)(as + c0 * 512 + lane * 8), 16, 0, 0);
        __builtin_amdgcn_global_load_lds((GUI*)ga1, (LUI*)(as + (c0 + 1) * 512 + lane * 8), 16, 0, 0);
        __builtin_amdgcn_global_load_lds((GUI*)gb0, (LUI*)(bs + c0 * 512 + lane * 8), 16, 0, 0);
        __builtin_amdgcn_global_load_lds((GUI*)gb1, (LUI*)(bs + (c0 + 1) * 512 + lane * 8), 16, 0, 0);
    };

    stage(0, 0);
    const int nit = K >> 5;
    for (int it = 0; it < nit; ++it) {
        __syncthreads();
        if (it + 1 < nit) stage((it + 1) << 5, (it + 1) & 1);

        const unsigned short* as = As + (it & 1) * 4096;
        const unsigned short* bs = Bs + (it & 1) * 4096;
        s16x8 a[4], b[4];
#pragma unroll
        for (int mt = 0; mt < 4; mt++)
            a[mt] = *(const s16x8*)(as + (wr + mt * 16 + lc) * 32 + quad * 8);
#pragma unroll
        for (int nb = 0; nb < 4; nb++)
            b[nb] = *(const s16x8*)(bs + (wc + nb * 16 + lc) * 32 + quad * 8);
#pragma unroll
        for (int mt = 0; mt < 4; mt++)
#pragma unroll
            for (int nb = 0; nb < 4; nb++)
                acc[mt][nb] = __builtin_amdgcn_mfma_f32_16x16x32_bf16(a[mt], b[nb], acc[mt][nb], 0, 0, 0);
    }
}

// ---------------------------------------------------------------------------
// QKV GEMM, 256x256 tile, 8-phase deep-pipelined schedule (T2+T3+T4+T5).
//  - BM=BN=256, BK=64, 8 waves (2M x 4N), 512 threads, 128 KiB LDS dbuf
//  - 1 half-tile (128x64, 2x global_load_lds/thread) staged per phase,
//    2 K-tiles ahead; counted vmcnt(6) at phases 4/8 only (never 0 in loop)
//  - LDS XOR swizzle: 16B granule slot ^= (row&7); applied as pre-swizzled
//    GLOBAL source + swizzled ds_read (global_load_lds writes linearly)
//  - s_setprio(1) around each 16-MFMA cluster
//  - epilogue: RoPE (table) + Q-scale + pack, as before
// Grid: 192 blocks (16 m x 12 n), XCD-bijective swizzle (192 % 8 == 0).
// ---------------------------------------------------------------------------
#define BAR    __builtin_amdgcn_s_barrier()
#define LGKM0  asm volatile("s_waitcnt lgkmcnt(0)" ::: "memory")
#define VMC6   asm volatile("s_waitcnt vmcnt(6)" ::: "memory")
#define VMC0   asm volatile("s_waitcnt vmcnt(0)" ::: "memory")

#define STG_A(BUF, HALF, T) do {                                                      \
    const unsigned short* s_ = gA + ((HALF) * 128) * DMODEL + (T) * 64;               \
    unsigned short* d_ = (unsigned short*)As + (BUF) * 16384 + (HALF) * 8192 + tid * 8;\
    __builtin_amdgcn_global_load_lds((GUI*)s_, (LUI*)d_, 16, 0, 0);                   \
    __builtin_amdgcn_global_load_lds((GUI*)(s_ + 64 * DMODEL), (LUI*)(d_ + 4096), 16, 0, 0); \
} while (0)

#define STG_B(BUF, HALF, T) do {                                                      \
    const unsigned short* s_ = gB + ((HALF) * 128) * DMODEL + (T) * 64;               \
    unsigned short* d_ = (unsigned short*)Bs + (BUF) * 16384 + (HALF) * 8192 + tid * 8;\
    __builtin_amdgcn_global_load_lds((GUI*)s_, (LUI*)d_, 16, 0, 0);                   \
    __builtin_amdgcn_global_load_lds((GUI*)(s_ + 64 * DMODEL), (LUI*)(d_ + 4096), 16, 0, 0); \
} while (0)

#define LDA(BUF, MQ) do {                                                             \
    _Pragma("unroll") for (int mt_ = 0; mt_ < 4; mt_++) {                             \
        const int r_ = wm * 64 + mt_ * 16 + lc;                                       \
        const int b_ = ((BUF) * 2 + (MQ)) * 8192 + r_ * 64;                           \
        const int sw_ = r_ & 7;                                                       \
        a[mt_][0] = *(const s16x8*)&As[b_ + ((quad ^ sw_) * 8)];                      \
        a[mt_][1] = *(const s16x8*)&As[b_ + (((4 + quad) ^ sw_) * 8)];               \
    } } while (0)

#define LDB(BREG, BUF, NQ) do {                                                       \
    _Pragma("unroll") for (int nb_ = 0; nb_ < 2; nb_++) {                             \
        const int r_ = wn * 32 + nb_ * 16 + lc;                                       \
        const int b_ = ((BUF) * 2 + (NQ)) * 8192 + r_ * 64;                           \
        const int sw_ = r_ & 7;                                                       \
        BREG[nb_][0] = *(const s16x8*)&Bs[b_ + ((quad ^ sw_) * 8)];                  \
        BREG[nb_][1] = *(const s16x8*)&Bs[b_ + (((4 + quad) ^ sw_) * 8)];            \
    } } while (0)

#define MM(MQ, NQ, BREG) do {                                                         \
    __builtin_amdgcn_s_setprio(1);                                                    \
    _Pragma("unroll") for (int mt_ = 0; mt_ < 4; mt_++)                               \
    _Pragma("unroll") for (int nb_ = 0; nb_ < 2; nb_++) {                             \
        acc[MQ][NQ][mt_][nb_] = __builtin_amdgcn_mfma_f32_16x16x32_bf16(             \
            a[mt_][0], BREG[nb_][0], acc[MQ][NQ][mt_][nb_], 0, 0, 0);                 \
        acc[MQ][NQ][mt_][nb_] = __builtin_amdgcn_mfma_f32_16x16x32_bf16(             \
            a[mt_][1], BREG[nb_][1], acc[MQ][NQ][mt_][nb_], 0, 0, 0);                 \
    }                                                                                 \
    __builtin_amdgcn_s_setprio(0); } while (0)

__global__ __launch_bounds__(512, 2) void gemm_qkv_rope_256(
    const unsigned short* __restrict__ xb, const unsigned short* __restrict__ Wt,
    const float2* __restrict__ rope_tab,
    unsigned short* __restrict__ Qb, unsigned short* __restrict__ Kb,
    unsigned short* __restrict__ Vb)
{
    __shared__ __align__(16) unsigned short As[2 * 2 * 128 * 64];  // 64 KiB
    __shared__ __align__(16) unsigned short Bs[2 * 2 * 128 * 64];  // 64 KiB

    const int tid  = threadIdx.x;
    const int lane = tid & 63;
    const int wid  = tid >> 6;       // 0..7
    const int wm   = wid >> 2;       // 0..1 (M)
    const int wn   = wid & 3;        // 0..3 (N)
    const int quad = lane >> 4;
    const int lc   = lane & 15;

    const int bid = blockIdx.x;                  // 0..191
    const int swz = (bid & 7) * 24 + (bid >> 3); // XCD-bijective (192 % 8 == 0)
    const int m0  = (swz / 12) * 256;
    const int n0  = (swz % 12) * 256;

    // staging geometry: thread covers LDS bytes [tid*16, +16) + i*8192 of a
    // half-tile; row = i*64 + (tid>>3), phys slot = tid&7; fetch the
    // pre-swizzled global granule so swizzled reads see logical data.
    const int srow = tid >> 3;                   // 0..63
    const int sg   = (tid & 7) ^ (srow & 7);     // source 16B granule
    const unsigned short* gA = xb + (size_t)(m0 + srow) * DMODEL + sg * 8;
    const unsigned short* gB = Wt + (size_t)(n0 + srow) * DMODEL + sg * 8;

    s16x8 a[4][2], b0[2][2], b1[2][2];
    f32x4 acc[2][2][4][2];
#pragma unroll
    for (int i = 0; i < 2; i++)
#pragma unroll
    for (int j = 0; j < 2; j++)
#pragma unroll
    for (int k = 0; k < 4; k++)
#pragma unroll
    for (int l = 0; l < 2; l++)
        acc[i][j][k][l] = (f32x4){0.f, 0.f, 0.f, 0.f};

    // ---- prologue: T0 fully + T1 {B0,A0,B1}; keep newest 6 loads in flight
    STG_A(0, 0, 0); STG_B(0, 0, 0); STG_B(0, 1, 0); STG_A(0, 1, 0);
    STG_B(1, 0, 1); STG_A(1, 0, 1); STG_B(1, 1, 1);
    VMC6;
    BAR;

    // ---- main loop: iteration = 2 K-tiles (buf0 then buf1), 8 phases
#pragma unroll 1
    for (int it = 0; it < 7; ++it) {
        const int t1 = 2 * it + 1, t2 = 2 * it + 2, t3 = 2 * it + 3;
        // P1: quadrant (0,0) of buf0
        LDA(0, 0); LDB(b0, 0, 0);
        STG_A(1, 1, t1);            // finish buf1 tile (A1)
        BAR; LGKM0;
        MM(0, 0, b0);
        BAR;
        // P2: (0,1)
        LDB(b1, 0, 1);
        STG_B(0, 0, t2);
        BAR; LGKM0;
        MM(0, 1, b1);
        BAR;
        // P3: (1,1)
        LDA(0, 1);
        STG_A(0, 0, t2);
        BAR; LGKM0;
        MM(1, 1, b1);
        BAR;
        // P4: (1,0)   [no new ds reads: a=A1 held, b0 held since P1]
        STG_B(0, 1, t2);
        BAR;
        MM(1, 0, b0);
        VMC6;                        // buf1 tile (staged P6-8 prev + P1) landed
        BAR;
        // P5: quadrant (0,0) of buf1
        LDA(1, 0); LDB(b0, 1, 0);
        STG_A(0, 1, t2);            // finish buf0 next tile (A1)
        BAR; LGKM0;
        MM(0, 0, b0);
        BAR;
        // P6: (0,1)
        LDB(b1, 1, 1);
        STG_B(1, 0, t3);
        BAR; LGKM0;
        MM(0, 1, b1);
        BAR;
        // P7: (1,1)
        LDA(1, 1);
        STG_A(1, 0, t3);
        BAR; LGKM0;
        MM(1, 1, b1);
        BAR;
        // P8: (1,0)
        STG_B(1, 1, t3);
        BAR;
        MM(1, 0, b0);
        VMC6;                        // buf0 next tile (staged P2-5) landed
        BAR;
    }

    // ---- peeled last iteration: tiles 14 (buf0) and 15 (buf1), drain
    LDA(0, 0); LDB(b0, 0, 0);
    STG_A(1, 1, 15);                 // last stage: T15.A1
    BAR; LGKM0; MM(0, 0, b0); BAR;
    LDB(b1, 0, 1);
    BAR; LGKM0; MM(0, 1, b1); BAR;
    LDA(0, 1);
    BAR; LGKM0; MM(1, 1, b1); BAR;
    BAR; MM(1, 0, b0);
    VMC0;                            // all of T15 landed
    BAR;
    LDA(1, 0); LDB(b0, 1, 0);
    BAR; LGKM0; MM(0, 0, b0); BAR;
    LDB(b1, 1, 1);
    BAR; LGKM0; MM(0, 1, b1); BAR;
    LDA(1, 1);
    BAR; LGKM0; MM(1, 1, b1); BAR;
    MM(1, 0, b0);

    // ---- epilogue: RoPE (Q/K) or pack-transpose (V)
    const int part = n0 >> 10;       // block lies entirely in one of q/k/v
    unsigned short* dst = (part == 0) ? Qb : (part == 1 ? Kb : Vb);
    const float scale = (part == 0) ? 0.125f * 1.4426950408889634f : 1.0f;

#pragma unroll
    for (int mq = 0; mq < 2; mq++)
#pragma unroll
    for (int nq = 0; nq < 2; nq++)
#pragma unroll
    for (int mt = 0; mt < 4; mt++)
#pragma unroll
    for (int nb = 0; nb < 2; nb++) {
        const int n = n0 + nq * 128 + wn * 32 + nb * 16 + lc;
        const int h = (n >> 6) & 15;
        const int d = n & 63;
        const int mb = m0 + mq * 128 + wm * 64 + mt * 16 + quad * 4;
        const f32x4 v = acc[mq][nq][mt][nb];
        if (part == 2) {
            const int bb = mb >> 11, t = mb & 2047;
            u16x4 pk;
            pk[0] = f2bf(v[0]); pk[1] = f2bf(v[1]);
            pk[2] = f2bf(v[2]); pk[3] = f2bf(v[3]);
            *(u16x4*)&dst[((size_t)(bb * NHEAD + h) * HDIM + d) * T_SEQ + t] = pk;
        } else {
            const size_t hb = (size_t)h * T_SEQ * HDIM + d;
            const int d2 = d >> 1;
            const float ssign = (lc & 1) ? 1.f : -1.f;
#pragma unroll
            for (int r = 0; r < 4; r++) {
                const float val = v[r];
                const float prt = __shfl_xor(val, 1);
                const int m = mb + r;
                const int bb = m >> 11, t = m & 2047;
                const float2 sc = rope_tab[t * 32 + d2];   // (cos, sin)
                const float res = fmaf(prt, ssign * sc.y, val * sc.x) * scale;
                dst[(size_t)bb * NHEAD * T_SEQ * HDIM + hb + (size_t)t * HDIM] = f2bf(res);
            }
        }
    }
}

// ---------------------------------------------------------------------------
// Out-proj GEMM (bf16 MFMA, dbuf): out[M,1024] fp32 = attnb x Wout_t^T.
// ---------------------------------------------------------------------------
__global__ __launch_bounds__(256) void gemm_out_mfma(
    const unsigned short* __restrict__ A, const unsigned short* __restrict__ Bt,
    float* __restrict__ C, int N, int K)
{
    __shared__ __align__(16) unsigned short As[2 * 128 * 32];
    __shared__ __align__(16) unsigned short Bs[2 * 128 * 32];

    const int id = blockIdx.x;            // 0..255
    const int n0 = (id & 7) * 128;
    const int m0 = (id >> 3) * 128;
    f32x4 acc[4][4];
    mfma_gemm_loop_db(A, Bt, As, Bs, m0, n0, K, acc);

    const int lane = threadIdx.x & 63;
    const int wave = threadIdx.x >> 6;
    const int quad = lane >> 4;
    const int lc   = lane & 15;
    const int wr   = (wave >> 1) * 64;
    const int wc   = (wave & 1) * 64;

#pragma unroll
    for (int mt = 0; mt < 4; mt++) {
        const int mb = m0 + wr + mt * 16 + quad * 4;
#pragma unroll
        for (int r = 0; r < 4; r++) {
            float* row = C + (size_t)(mb + r) * N + n0 + wc;
#pragma unroll
            for (int nb = 0; nb < 4; nb++)
                row[nb * 16 + lc] = acc[mt][nb][r];
        }
    }
}

// ---------------------------------------------------------------------------
// MFMA causal flash attention v7 (XCD-affine, balanced two-pass, dbuf K/V).
// ---------------------------------------------------------------------------
__global__ __launch_bounds__(256, 2) void attn_mfma7(
    const unsigned short* __restrict__ Qb, const unsigned short* __restrict__ Kb,
    const unsigned short* __restrict__ Vtg, unsigned short* __restrict__ out)
{
    __shared__ __align__(16) unsigned short Ks[2][64 * 64];
    __shared__ __align__(16) unsigned short Vs[2][64 * 64];
    __shared__ __align__(16) unsigned short Ps[4][16 * 72];

    const int tid  = threadIdx.x;
    const int lane = tid & 63;
    const int wave = tid >> 6;           // 0..3
    const int quad = lane >> 4;
    const int lc   = lane & 15;
    const int rsw  = lc & 7;

    const int id   = blockIdx.x;             // 0..511
    const int slot = id >> 3;                // 0..63
    const int bh   = (id & 7) + 8 * (slot & 3);   // 4 heads per XCD
    const int xb   = slot >> 2;              // 0..15

    const size_t headK = (size_t)bh * T_SEQ * HDIM;   // Q,K: (BH,T,64)
    const size_t headV = (size_t)bh * HDIM * T_SEQ;   // Vt:  (BH,64,T)
    const int b = bh >> 4;
    const int h = bh & 15;

    const int c0   = wave * 2;
    const int krow = lane >> 3;
    const int d8sw = (lane & 7) ^ krow;
    unsigned short* pw = Ps[wave];

#pragma unroll
    for (int pass = 0; pass < 2; pass++) {
        const int qb = pass ? (31 - xb) : xb;
        const int t0 = qb * 64;
        const int n_tiles = qb + 1;

        s16x8 qf0, qf1;
        {
            const size_t qrow = headK + (size_t)(t0 + wave * 16 + lc) * HDIM;
            qf0 = *(const s16x8*)(Qb + qrow + quad * 8);
            qf1 = *(const s16x8*)(Qb + qrow + 32 + quad * 8);
        }

        f32x4 o[4];
        float m_i = -INFINITY, l_i = 0.f;
#pragma unroll
        for (int db = 0; db < 4; db++)
            o[db] = (f32x4){0.f, 0.f, 0.f, 0.f};

        auto stage = [&](int s0, int buf) {
            const unsigned short* gk0 = Kb  + headK + (size_t)(s0 + c0 * 8 + krow) * HDIM + d8sw * 8;
            const unsigned short* gk1 = Kb  + headK + (size_t)(s0 + c0 * 8 + 8 + krow) * HDIM + d8sw * 8;
            const unsigned short* gv0 = Vtg + headV + (size_t)(c0 * 8 + krow) * T_SEQ + s0 + d8sw * 8;
            const unsigned short* gv1 = Vtg + headV + (size_t)(c0 * 8 + 8 + krow) * T_SEQ + s0 + d8sw * 8;
            __builtin_amdgcn_global_load_lds((GUI*)gk0, (LUI*)(Ks[buf] + c0 * 512 + lane * 8), 16, 0, 0);
            __builtin_amdgcn_global_load_lds((GUI*)gk1, (LUI*)(Ks[buf] + (c0 + 1) * 512 + lane * 8), 16, 0, 0);
            __builtin_amdgcn_global_load_lds((GUI*)gv0, (LUI*)(Vs[buf] + c0 * 512 + lane * 8), 16, 0, 0);
            __builtin_amdgcn_global_load_lds((GUI*)gv1, (LUI*)(Vs[buf] + (c0 + 1) * 512 + lane * 8), 16, 0, 0);
        };

        __syncthreads();
        stage(0, 0);

        for (int tile = 0; tile < n_tiles; ++tile) {
            const int s0 = tile * 64;
            const int buf = tile & 1;
            __syncthreads();
            if (tile + 1 < n_tiles) stage(s0 + 64, buf ^ 1);

            const unsigned short* ks = Ks[buf];
            const unsigned short* vs = Vs[buf];

            f32x4 st[4];
#pragma unroll
            for (int kb = 0; kb < 4; kb++) {
                const s16x8 ka0 = *(const s16x8*)&ks[(kb * 16 + lc) * 64 + ((quad ^ rsw) * 8)];
                const s16x8 ka1 = *(const s16x8*)&ks[(kb * 16 + lc) * 64 + (((4 + quad) ^ rsw) * 8)];
                f32x4 z = (f32x4){0.f, 0.f, 0.f, 0.f};
                z = __builtin_amdgcn_mfma_f32_16x16x32_bf16(ka0, qf0, z, 0, 0, 0);
                z = __builtin_amdgcn_mfma_f32_16x16x32_bf16(ka1, qf1, z, 0, 0, 0);
                st[kb] = z;
            }

            s16x8 va[4][2];
#pragma unroll
            for (int db = 0; db < 4; db++) {
                va[db][0] = *(const s16x8*)&vs[(db * 16 + lc) * 64 + ((quad ^ rsw) * 8)];
                va[db][1] = *(const s16x8*)&vs[(db * 16 + lc) * 64 + (((4 + quad) ^ rsw) * 8)];
            }

            if (tile == n_tiles - 1) {
                const int qrow = t0 + wave * 16 + lc;
#pragma unroll
                for (int kb = 0; kb < 4; kb++) {
                    const int key = s0 + kb * 16 + quad * 4;
#pragma unroll
                    for (int r = 0; r < 4; r++)
                        if (key + r > qrow) st[kb][r] = -INFINITY;
                }
            }

            float mt = st[0][0];
#pragma unroll
            for (int kb = 0; kb < 4; kb++)
#pragma unroll
                for (int r = 0; r < 4; r++) mt = fmaxf(mt, st[kb][r]);
            mt = fmaxf(mt, __shfl_xor(mt, 16));
            mt = fmaxf(mt, __shfl_xor(mt, 32));
            const float mn = fmaxf(m_i, mt);
            const float alpha = __builtin_amdgcn_exp2f(m_i - mn);
            m_i = mn;
            float rs = 0.f;
#pragma unroll
            for (int kb = 0; kb < 4; kb++)
#pragma unroll
                for (int r = 0; r < 4; r++) {
                    const float p = __builtin_amdgcn_exp2f(st[kb][r] - mn);
                    st[kb][r] = p;
                    rs += p;
                }
            rs += __shfl_xor(rs, 16);
            rs += __shfl_xor(rs, 32);
            l_i = l_i * alpha + rs;
#pragma unroll
            for (int db = 0; db < 4; db++) {
                o[db][0] *= alpha; o[db][1] *= alpha;
                o[db][2] *= alpha; o[db][3] *= alpha;
            }
#pragma unroll
            for (int kb = 0; kb < 4; kb++) {
                u32x2 pk;
                pk[0] = f2bf_pack2(st[kb][0], st[kb][1]);
                pk[1] = f2bf_pack2(st[kb][2], st[kb][3]);
                *(u32x2*)&pw[lc * 72 + kb * 16 + quad * 4] = pk;
            }
            const s16x8 pb0 = *(const s16x8*)&pw[lc * 72 + quad * 8];
            const s16x8 pb1 = *(const s16x8*)&pw[lc * 72 + 32 + quad * 8];
#pragma unroll
            for (int db = 0; db < 4; db++) {
                o[db] = __builtin_amdgcn_mfma_f32_16x16x32_bf16(va[db][0], pb0, o[db], 0, 0, 0);
                o[db] = __builtin_amdgcn_mfma_f32_16x16x32_bf16(va[db][1], pb1, o[db], 0, 0, 0);
            }
        }

        {
            const float inv_l = 1.f / l_i;
            const int t = t0 + wave * 16 + lc;
            unsigned short* orow = out + (size_t)(b * T_SEQ + t) * DMODEL + h * HDIM + quad * 4;
#pragma unroll
            for (int db = 0; db < 4; db++) {
                u32x2 pk;
                pk[0] = f2bf_pack2(o[db][0] * inv_l, o[db][1] * inv_l);
                pk[1] = f2bf_pack2(o[db][2] * inv_l, o[db][3] * inv_l);
                *(u32x2*)(orow + db * 16) = pk;
            }
        }
    }
}

// ---------------------------------------------------------------------------
extern "C" void kernel_launch(void* const* d_in, const int* in_sizes, int n_in,
                              void* d_out, int out_size, void* d_ws, size_t ws_size,
                              hipStream_t stream)
{
    const float* x    = (const float*)d_in[0];   // (B,T,D) fp32
    const float* Wqkv = (const float*)d_in[1];   // (D,3D) fp32
    const float* Wout = (const float*)d_in[2];   // (D,D) fp32
    // d_in[3] attn_mask: causal triu(k=1), applied analytically.

    float* out = (float*)d_out;

    char* ws = (char*)d_ws;
    unsigned short* attnb  = (unsigned short*)(ws);               // (B,T,D) bf16, 8 MB
    unsigned short* Qb     = (unsigned short*)(ws + (8u  << 20)); // (B,H,T,64)
    unsigned short* Kb     = (unsigned short*)(ws + (16u << 20)); // (B,H,T,64)
    unsigned short* Vt     = (unsigned short*)(ws + (24u << 20)); // (B,H,64,T)
    unsigned short* xbuf   = (unsigned short*)(ws + (32u << 20)); // (M,K) bf16
    unsigned short* Wqkv_t = (unsigned short*)(ws + (40u << 20)); // (3D,D) bf16
    unsigned short* Wout_t = (unsigned short*)(ws + (46u << 20)); // (D,D) bf16
    float2*         ropeT  = (float2*)       (ws + (48u << 20)); // 2048x32 float2, 512 KB

    // 0) fused prep: convert x, transpose weights, build RoPE table
    prep_fused<<<dim3(3328), 256, 0, stream>>>(x, Wqkv, Wout, xbuf, Wqkv_t, Wout_t, ropeT);

    // 1) QKV GEMM, 256^2 8-phase pipeline + RoPE table + scale + pack
    gemm_qkv_rope_256<<<dim3(192), 512, 0, stream>>>(xbuf, Wqkv_t, ropeT, Qb, Kb, Vt);

    // 2) MFMA causal flash attention v7 (XCD-affine) -> attnb (B,T,D) bf16
    attn_mfma7<<<dim3(512), 256, 0, stream>>>(Qb, Kb, Vt, attnb);

    // 3) out = attnb @ Wout  (fp32 out, dbuf, XCD-affine)
    gemm_out_mfma<<<dim3(256), 256, 0, stream>>>(attnb, Wout_t, out, DMODEL, DMODEL);
}

// Round 2
// 195.489 us; speedup vs baseline: 1.0207x; 1.0111x over previous
//
#include <hip/hip_runtime.h>
#include <math.h>

#define BATCH   2
#define T_SEQ   2048
#define DMODEL  1024
#define NHEAD   16
#define HDIM    64

typedef short s16x8 __attribute__((ext_vector_type(8)));
typedef unsigned short u16x8 __attribute__((ext_vector_type(8)));
typedef unsigned short u16x4 __attribute__((ext_vector_type(4)));
typedef unsigned int u32x2 __attribute__((ext_vector_type(2)));
typedef float f32x4 __attribute__((ext_vector_type(4)));

typedef const unsigned int __attribute__((address_space(1))) GUI;
typedef unsigned int __attribute__((address_space(3))) LUI;

// fp32 -> bf16 round-to-nearest-even (bit pattern)
static __device__ __forceinline__ unsigned short f2bf(float f) {
    unsigned int u = __float_as_uint(f);
    u += 0x7fffu + ((u >> 16) & 1u);
    return (unsigned short)(u >> 16);
}

// two fp32 -> packed bf16x2 (round-half-up) via one v_perm_b32
static __device__ __forceinline__ unsigned int f2bf_pack2(float a, float b) {
    const unsigned int ua = __float_as_uint(a) + 0x8000u;
    const unsigned int ub = __float_as_uint(b) + 0x8000u;
    return __builtin_amdgcn_perm(ub, ua, 0x07060302u);
}

// ---------------------------------------------------------------------------
// Fused prep: blocks 0..2047 convert x -> bf16; 2048..2815 transpose Wqkv;
// 2816..3071 transpose Wout; 3072..3327 build RoPE cos/sin table
// ---------------------------------------------------------------------------
__global__ __launch_bounds__(256) void prep_fused(
    const float* __restrict__ x, const float* __restrict__ Wqkv,
    const float* __restrict__ Wout,
    unsigned short* __restrict__ xb, unsigned short* __restrict__ Wqkv_t,
    unsigned short* __restrict__ Wout_t, float2* __restrict__ rope_tab)
{
    __shared__ unsigned short tile[64][68];
    const int bid = blockIdx.x;
    const int tid = threadIdx.x;

    if (bid < 2048) {
        const int i = bid * 256 + tid;
        const float4 a = ((const float4*)x)[2 * i];
        const float4 b = ((const float4*)x)[2 * i + 1];
        u16x8 r;
        r[0] = f2bf(a.x); r[1] = f2bf(a.y); r[2] = f2bf(a.z); r[3] = f2bf(a.w);
        r[4] = f2bf(b.x); r[5] = f2bf(b.y); r[6] = f2bf(b.z); r[7] = f2bf(b.w);
        ((u16x8*)xb)[i] = r;
        return;
    }
    if (bid >= 3072) {
        const int idx = (bid - 3072) * 256 + tid;
        const int t = idx >> 5;
        const int d2 = idx & 31;
        const float inv_freq = exp2f(-(float)d2 * 0.41524101186092029f); // log2(1e4)/32
        float s, c;
        sincosf((float)t * inv_freq, &s, &c);
        rope_tab[idx] = make_float2(c, s);
        return;
    }

    const float* src;
    unsigned short* dst;
    int R, C, bx, by;
    if (bid < 2816) {
        const int id = bid - 2048;
        src = Wqkv; dst = Wqkv_t; R = DMODEL; C = 3 * DMODEL;
        bx = id % 48; by = id / 48;
    } else {
        const int id = bid - 2816;
        src = Wout; dst = Wout_t; R = DMODEL; C = DMODEL;
        bx = id % 16; by = id / 16;
    }
    const int tc0 = bx * 64;
    const int tr0 = by * 64;
    const int tx = tid & 63;
    const int ty = tid >> 6;
#pragma unroll
    for (int i = 0; i < 16; i++) {
        const int rr = i * 4 + ty;
        tile[tx][rr] = f2bf(src[(size_t)(tr0 + rr) * C + tc0 + tx]);
    }
    __syncthreads();
#pragma unroll
    for (int i = 0; i < 16; i++) {
        const int cc = i * 4 + ty;
        dst[(size_t)(tc0 + cc) * R + tr0 + tx] = tile[cc][tx];
    }
}

// ---------------------------------------------------------------------------
// Shared MFMA GEMM main loop, DOUBLE-BUFFERED, one barrier per K-slice.
// (still used by gemm_out_mfma)
// ---------------------------------------------------------------------------
__device__ __forceinline__ void mfma_gemm_loop_db(
    const unsigned short* __restrict__ A, const unsigned short* __restrict__ Bt,
    unsigned short* As, unsigned short* Bs,
    int m0, int n0, int K, f32x4 acc[4][4])
{
    const int tid  = threadIdx.x;
    const int wave = tid >> 6;
    const int lane = tid & 63;
    const int quad = lane >> 4;
    const int lc   = lane & 15;
    const int wr   = (wave >> 1) * 64;
    const int wc   = (wave & 1) * 64;

    const int c0    = wave * 2;
    const int srow0 = c0 * 16 + (lane >> 2);
    const int scol  = (lane & 3) * 8;

#pragma unroll
    for (int i = 0; i < 4; i++)
#pragma unroll
        for (int j = 0; j < 4; j++)
            acc[i][j] = (f32x4){0.f, 0.f, 0.f, 0.f};

    auto stage = [&](int kt, int buf) {
        const unsigned short* ga0 = A + (size_t)(m0 + srow0) * K + kt + scol;
        const unsigned short* ga1 = A + (size_t)(m0 + srow0 + 16) * K + kt + scol;
        const unsigned short* gb0 = Bt + (size_t)(n0 + srow0) * K + kt + scol;
        const unsigned short* gb1 = Bt + (size_t)(n0 + srow0 + 16) * K + kt + scol;
        unsigned short* as = As + buf * 4096;
        unsigned short* bs = Bs + buf * 4096;
        __builtin_amdgcn_global_load_lds((GUI*)ga0, (LUI*)(as + c0 * 512 + lane * 8), 16, 0, 0);
        __builtin_amdgcn_global_load_lds((GUI*)ga1, (LUI*)(as + (c0 + 1) * 512 + lane * 8), 16, 0, 0);
        __builtin_amdgcn_global_load_lds((GUI*)gb0, (LUI*)(bs + c0 * 512 + lane * 8), 16, 0, 0);
        __builtin_amdgcn_global_load_lds((GUI*)gb1, (LUI*)(bs + (c0 + 1) * 512 + lane * 8), 16, 0, 0);
    };

    stage(0, 0);
    const int nit = K >> 5;
    for (int it = 0; it < nit; ++it) {
        __syncthreads();
        if (it + 1 < nit) stage((it + 1) << 5, (it + 1) & 1);

        const unsigned short* as = As + (it & 1) * 4096;
        const unsigned short* bs = Bs + (it & 1) * 4096;
        s16x8 a[4], b[4];
#pragma unroll
        for (int mt = 0; mt < 4; mt++)
            a[mt] = *(const s16x8*)(as + (wr + mt * 16 + lc) * 32 + quad * 8);
#pragma unroll
        for (int nb = 0; nb < 4; nb++)
            b[nb] = *(const s16x8*)(bs + (wc + nb * 16 + lc) * 32 + quad * 8);
#pragma unroll
        for (int mt = 0; mt < 4; mt++)
#pragma unroll
            for (int nb = 0; nb < 4; nb++)
                acc[mt][nb] = __builtin_amdgcn_mfma_f32_16x16x32_bf16(a[mt], b[nb], acc[mt][nb], 0, 0, 0);
    }
}

// ---------------------------------------------------------------------------
// QKV GEMM, 256x256 tile, 8-phase deep-pipelined schedule (T2+T3+T4+T5).
// launch_bounds(512,1): LDS (128 KiB) already forces 1 block/CU, so give the
// allocator the full 512-VGPR budget — the (512,2) cap risked acc spills.
// ---------------------------------------------------------------------------
#define BAR    __builtin_amdgcn_s_barrier()
#define LGKM0  asm volatile("s_waitcnt lgkmcnt(0)" ::: "memory")
#define VMC6   asm volatile("s_waitcnt vmcnt(6)" ::: "memory")
#define VMC0   asm volatile("s_waitcnt vmcnt(0)" ::: "memory")

#define STG_A(BUF, HALF, T) do {                                                      \
    const unsigned short* s_ = gA + ((HALF) * 128) * DMODEL + (T) * 64;               \
    unsigned short* d_ = (unsigned short*)As + (BUF) * 16384 + (HALF) * 8192 + tid * 8;\
    __builtin_amdgcn_global_load_lds((GUI*)s_, (LUI*)d_, 16, 0, 0);                   \
    __builtin_amdgcn_global_load_lds((GUI*)(s_ + 64 * DMODEL), (LUI*)(d_ + 4096), 16, 0, 0); \
} while (0)

#define STG_B(BUF, HALF, T) do {                                                      \
    const unsigned short* s_ = gB + ((HALF) * 128) * DMODEL + (T) * 64;               \
    unsigned short* d_ = (unsigned short*)Bs + (BUF) * 16384 + (HALF) * 8192 + tid * 8;\
    __builtin_amdgcn_global_load_lds((GUI*)s_, (LUI*)d_, 16, 0, 0);                   \
    __builtin_amdgcn_global_load_lds((GUI*)(s_ + 64 * DMODEL), (LUI*)(d_ + 4096), 16, 0, 0); \
} while (0)

#define LDA(BUF, MQ) do {                                                             \
    _Pragma("unroll") for (int mt_ = 0; mt_ < 4; mt_++) {                             \
        const int r_ = wm * 64 + mt_ * 16 + lc;                                       \
        const int b_ = ((BUF) * 2 + (MQ)) * 8192 + r_ * 64;                           \
        const int sw_ = r_ & 7;                                                       \
        a[mt_][0] = *(const s16x8*)&As[b_ + ((quad ^ sw_) * 8)];                      \
        a[mt_][1] = *(const s16x8*)&As[b_ + (((4 + quad) ^ sw_) * 8)];               \
    } } while (0)

#define LDB(BREG, BUF, NQ) do {                                                       \
    _Pragma("unroll") for (int nb_ = 0; nb_ < 2; nb_++) {                             \
        const int r_ = wn * 32 + nb_ * 16 + lc;                                       \
        const int b_ = ((BUF) * 2 + (NQ)) * 8192 + r_ * 64;                           \
        const int sw_ = r_ & 7;                                                       \
        BREG[nb_][0] = *(const s16x8*)&Bs[b_ + ((quad ^ sw_) * 8)];                  \
        BREG[nb_][1] = *(const s16x8*)&Bs[b_ + (((4 + quad) ^ sw_) * 8)];            \
    } } while (0)

#define MM(MQ, NQ, BREG) do {                                                         \
    __builtin_amdgcn_s_setprio(1);                                                    \
    _Pragma("unroll") for (int mt_ = 0; mt_ < 4; mt_++)                               \
    _Pragma("unroll") for (int nb_ = 0; nb_ < 2; nb_++) {                             \
        acc[MQ][NQ][mt_][nb_] = __builtin_amdgcn_mfma_f32_16x16x32_bf16(             \
            a[mt_][0], BREG[nb_][0], acc[MQ][NQ][mt_][nb_], 0, 0, 0);                 \
        acc[MQ][NQ][mt_][nb_] = __builtin_amdgcn_mfma_f32_16x16x32_bf16(             \
            a[mt_][1], BREG[nb_][1], acc[MQ][NQ][mt_][nb_], 0, 0, 0);                 \
    }                                                                                 \
    __builtin_amdgcn_s_setprio(0); } while (0)

__global__ __launch_bounds__(512, 1) void gemm_qkv_rope_256(
    const unsigned short* __restrict__ xb, const unsigned short* __restrict__ Wt,
    const float2* __restrict__ rope_tab,
    unsigned short* __restrict__ Qb, unsigned short* __restrict__ Kb,
    unsigned short* __restrict__ Vb)
{
    __shared__ __align__(16) unsigned short As[2 * 2 * 128 * 64];  // 64 KiB
    __shared__ __align__(16) unsigned short Bs[2 * 2 * 128 * 64];  // 64 KiB

    const int tid  = threadIdx.x;
    const int lane = tid & 63;
    const int wid  = tid >> 6;       // 0..7
    const int wm   = wid >> 2;       // 0..1 (M)
    const int wn   = wid & 3;        // 0..3 (N)
    const int quad = lane >> 4;
    const int lc   = lane & 15;

    const int bid = blockIdx.x;                  // 0..191
    const int swz = (bid & 7) * 24 + (bid >> 3); // XCD-bijective (192 % 8 == 0)
    const int m0  = (swz / 12) * 256;
    const int n0  = (swz % 12) * 256;

    const int srow = tid >> 3;                   // 0..63
    const int sg   = (tid & 7) ^ (srow & 7);     // pre-swizzled source granule
    const unsigned short* gA = xb + (size_t)(m0 + srow) * DMODEL + sg * 8;
    const unsigned short* gB = Wt + (size_t)(n0 + srow) * DMODEL + sg * 8;

    s16x8 a[4][2], b0[2][2], b1[2][2];
    f32x4 acc[2][2][4][2];
#pragma unroll
    for (int i = 0; i < 2; i++)
#pragma unroll
    for (int j = 0; j < 2; j++)
#pragma unroll
    for (int k = 0; k < 4; k++)
#pragma unroll
    for (int l = 0; l < 2; l++)
        acc[i][j][k][l] = (f32x4){0.f, 0.f, 0.f, 0.f};

    // ---- prologue: T0 fully + T1 {B0,A0,B1}; keep newest 6 loads in flight
    STG_A(0, 0, 0); STG_B(0, 0, 0); STG_B(0, 1, 0); STG_A(0, 1, 0);
    STG_B(1, 0, 1); STG_A(1, 0, 1); STG_B(1, 1, 1);
    VMC6;
    BAR;

    // ---- main loop: iteration = 2 K-tiles (buf0 then buf1), 8 phases
#pragma unroll 1
    for (int it = 0; it < 7; ++it) {
        const int t1 = 2 * it + 1, t2 = 2 * it + 2, t3 = 2 * it + 3;
        // P1: quadrant (0,0) of buf0
        LDA(0, 0); LDB(b0, 0, 0);
        STG_A(1, 1, t1);            // finish buf1 tile (A1)
        BAR; LGKM0;
        MM(0, 0, b0);
        BAR;
        // P2: (0,1)
        LDB(b1, 0, 1);
        STG_B(0, 0, t2);
        BAR; LGKM0;
        MM(0, 1, b1);
        BAR;
        // P3: (1,1)
        LDA(0, 1);
        STG_A(0, 0, t2);
        BAR; LGKM0;
        MM(1, 1, b1);
        BAR;
        // P4: (1,0)
        STG_B(0, 1, t2);
        BAR;
        MM(1, 0, b0);
        VMC6;                        // buf1 tile landed
        BAR;
        // P5: quadrant (0,0) of buf1
        LDA(1, 0); LDB(b0, 1, 0);
        STG_A(0, 1, t2);
        BAR; LGKM0;
        MM(0, 0, b0);
        BAR;
        // P6: (0,1)
        LDB(b1, 1, 1);
        STG_B(1, 0, t3);
        BAR; LGKM0;
        MM(0, 1, b1);
        BAR;
        // P7: (1,1)
        LDA(1, 1);
        STG_A(1, 0, t3);
        BAR; LGKM0;
        MM(1, 1, b1);
        BAR;
        // P8: (1,0)
        STG_B(1, 1, t3);
        BAR;
        MM(1, 0, b0);
        VMC6;                        // buf0 next tile landed
        BAR;
    }

    // ---- peeled last iteration: tiles 14 (buf0) and 15 (buf1), drain
    LDA(0, 0); LDB(b0, 0, 0);
    STG_A(1, 1, 15);
    BAR; LGKM0; MM(0, 0, b0); BAR;
    LDB(b1, 0, 1);
    BAR; LGKM0; MM(0, 1, b1); BAR;
    LDA(0, 1);
    BAR; LGKM0; MM(1, 1, b1); BAR;
    BAR; MM(1, 0, b0);
    VMC0;
    BAR;
    LDA(1, 0); LDB(b0, 1, 0);
    BAR; LGKM0; MM(0, 0, b0); BAR;
    LDB(b1, 1, 1);
    BAR; LGKM0; MM(0, 1, b1); BAR;
    LDA(1, 1);
    BAR; LGKM0; MM(1, 1, b1); BAR;
    MM(1, 0, b0);

    // ---- epilogue: RoPE (Q/K) or pack-transpose (V)
    const int part = n0 >> 10;
    unsigned short* dst = (part == 0) ? Qb : (part == 1 ? Kb : Vb);
    const float scale = (part == 0) ? 0.125f * 1.4426950408889634f : 1.0f;

#pragma unroll
    for (int mq = 0; mq < 2; mq++)
#pragma unroll
    for (int nq = 0; nq < 2; nq++)
#pragma unroll
    for (int mt = 0; mt < 4; mt++)
#pragma unroll
    for (int nb = 0; nb < 2; nb++) {
        const int n = n0 + nq * 128 + wn * 32 + nb * 16 + lc;
        const int h = (n >> 6) & 15;
        const int d = n & 63;
        const int mb = m0 + mq * 128 + wm * 64 + mt * 16 + quad * 4;
        const f32x4 v = acc[mq][nq][mt][nb];
        if (part == 2) {
            const int bb = mb >> 11, t = mb & 2047;
            u16x4 pk;
            pk[0] = f2bf(v[0]); pk[1] = f2bf(v[1]);
            pk[2] = f2bf(v[2]); pk[3] = f2bf(v[3]);
            *(u16x4*)&dst[((size_t)(bb * NHEAD + h) * HDIM + d) * T_SEQ + t] = pk;
        } else {
            const size_t hb = (size_t)h * T_SEQ * HDIM + d;
            const int d2 = d >> 1;
            const float ssign = (lc & 1) ? 1.f : -1.f;
#pragma unroll
            for (int r = 0; r < 4; r++) {
                const float val = v[r];
                const float prt = __shfl_xor(val, 1);
                const int m = mb + r;
                const int bb = m >> 11, t = m & 2047;
                const float2 sc = rope_tab[t * 32 + d2];   // (cos, sin)
                const float res = fmaf(prt, ssign * sc.y, val * sc.x) * scale;
                dst[(size_t)bb * NHEAD * T_SEQ * HDIM + hb + (size_t)t * HDIM] = f2bf(res);
            }
        }
    }
}

// ---------------------------------------------------------------------------
// Out-proj GEMM (bf16 MFMA, dbuf): out[M,1024] fp32 = attnb x Wout_t^T.
// ---------------------------------------------------------------------------
__global__ __launch_bounds__(256) void gemm_out_mfma(
    const unsigned short* __restrict__ A, const unsigned short* __restrict__ Bt,
    float* __restrict__ C, int N, int K)
{
    __shared__ __align__(16) unsigned short As[2 * 128 * 32];
    __shared__ __align__(16) unsigned short Bs[2 * 128 * 32];

    const int id = blockIdx.x;            // 0..255
    const int n0 = (id & 7) * 128;
    const int m0 = (id >> 3) * 128;
    f32x4 acc[4][4];
    mfma_gemm_loop_db(A, Bt, As, Bs, m0, n0, K, acc);

    const int lane = threadIdx.x & 63;
    const int wave = threadIdx.x >> 6;
    const int quad = lane >> 4;
    const int lc   = lane & 15;
    const int wr   = (wave >> 1) * 64;
    const int wc   = (wave & 1) * 64;

#pragma unroll
    for (int mt = 0; mt < 4; mt++) {
        const int mb = m0 + wr + mt * 16 + quad * 4;
#pragma unroll
        for (int r = 0; r < 4; r++) {
            float* row = C + (size_t)(mb + r) * N + n0 + wc;
#pragma unroll
            for (int nb = 0; nb < 4; nb++)
                row[nb * 16 + lc] = acc[mt][nb][r];
        }
    }
}

// ---------------------------------------------------------------------------
// MFMA causal flash attention v8: v7 + T13 defer-max (THR=8 in log2 domain),
// T5 setprio around MFMA clusters, tree-shaped max/sum reductions (v_max3).
// ---------------------------------------------------------------------------
__global__ __launch_bounds__(256, 2) void attn_mfma8(
    const unsigned short* __restrict__ Qb, const unsigned short* __restrict__ Kb,
    const unsigned short* __restrict__ Vtg, unsigned short* __restrict__ out)
{
    __shared__ __align__(16) unsigned short Ks[2][64 * 64];
    __shared__ __align__(16) unsigned short Vs[2][64 * 64];
    __shared__ __align__(16) unsigned short Ps[4][16 * 72];

    const int tid  = threadIdx.x;
    const int lane = tid & 63;
    const int wave = tid >> 6;           // 0..3
    const int quad = lane >> 4;
    const int lc   = lane & 15;
    const int rsw  = lc & 7;

    const int id   = blockIdx.x;             // 0..511
    const int slot = id >> 3;                // 0..63
    const int bh   = (id & 7) + 8 * (slot & 3);   // 4 heads per XCD
    const int xb   = slot >> 2;              // 0..15

    const size_t headK = (size_t)bh * T_SEQ * HDIM;   // Q,K: (BH,T,64)
    const size_t headV = (size_t)bh * HDIM * T_SEQ;   // Vt:  (BH,64,T)
    const int b = bh >> 4;
    const int h = bh & 15;

    const int c0   = wave * 2;
    const int krow = lane >> 3;
    const int d8sw = (lane & 7) ^ krow;
    unsigned short* pw = Ps[wave];

#pragma unroll
    for (int pass = 0; pass < 2; pass++) {
        const int qb = pass ? (31 - xb) : xb;
        const int t0 = qb * 64;
        const int n_tiles = qb + 1;

        s16x8 qf0, qf1;
        {
            const size_t qrow = headK + (size_t)(t0 + wave * 16 + lc) * HDIM;
            qf0 = *(const s16x8*)(Qb + qrow + quad * 8);
            qf1 = *(const s16x8*)(Qb + qrow + 32 + quad * 8);
        }

        f32x4 o[4];
        float m_i = -INFINITY, l_i = 0.f;
#pragma unroll
        for (int db = 0; db < 4; db++)
            o[db] = (f32x4){0.f, 0.f, 0.f, 0.f};

        auto stage = [&](int s0, int buf) {
            const unsigned short* gk0 = Kb  + headK + (size_t)(s0 + c0 * 8 + krow) * HDIM + d8sw * 8;
            const unsigned short* gk1 = Kb  + headK + (size_t)(s0 + c0 * 8 + 8 + krow) * HDIM + d8sw * 8;
            const unsigned short* gv0 = Vtg + headV + (size_t)(c0 * 8 + krow) * T_SEQ + s0 + d8sw * 8;
            const unsigned short* gv1 = Vtg + headV + (size_t)(c0 * 8 + 8 + krow) * T_SEQ + s0 + d8sw * 8;
            __builtin_amdgcn_global_load_lds((GUI*)gk0, (LUI*)(Ks[buf] + c0 * 512 + lane * 8), 16, 0, 0);
            __builtin_amdgcn_global_load_lds((GUI*)gk1, (LUI*)(Ks[buf] + (c0 + 1) * 512 + lane * 8), 16, 0, 0);
            __builtin_amdgcn_global_load_lds((GUI*)gv0, (LUI*)(Vs[buf] + c0 * 512 + lane * 8), 16, 0, 0);
            __builtin_amdgcn_global_load_lds((GUI*)gv1, (LUI*)(Vs[buf] + (c0 + 1) * 512 + lane * 8), 16, 0, 0);
        };

        __syncthreads();
        stage(0, 0);

        for (int tile = 0; tile < n_tiles; ++tile) {
            const int s0 = tile * 64;
            const int buf = tile & 1;
            __syncthreads();
            if (tile + 1 < n_tiles) stage(s0 + 64, buf ^ 1);

            const unsigned short* ks = Ks[buf];
            const unsigned short* vs = Vs[buf];

            f32x4 st[4];
            __builtin_amdgcn_s_setprio(1);
#pragma unroll
            for (int kb = 0; kb < 4; kb++) {
                const s16x8 ka0 = *(const s16x8*)&ks[(kb * 16 + lc) * 64 + ((quad ^ rsw) * 8)];
                const s16x8 ka1 = *(const s16x8*)&ks[(kb * 16 + lc) * 64 + (((4 + quad) ^ rsw) * 8)];
                f32x4 z = (f32x4){0.f, 0.f, 0.f, 0.f};
                z = __builtin_amdgcn_mfma_f32_16x16x32_bf16(ka0, qf0, z, 0, 0, 0);
                z = __builtin_amdgcn_mfma_f32_16x16x32_bf16(ka1, qf1, z, 0, 0, 0);
                st[kb] = z;
            }
            __builtin_amdgcn_s_setprio(0);

            s16x8 va[4][2];
#pragma unroll
            for (int db = 0; db < 4; db++) {
                va[db][0] = *(const s16x8*)&vs[(db * 16 + lc) * 64 + ((quad ^ rsw) * 8)];
                va[db][1] = *(const s16x8*)&vs[(db * 16 + lc) * 64 + (((4 + quad) ^ rsw) * 8)];
            }

            if (tile == n_tiles - 1) {
                const int qrow = t0 + wave * 16 + lc;
#pragma unroll
                for (int kb = 0; kb < 4; kb++) {
                    const int key = s0 + kb * 16 + quad * 4;
#pragma unroll
                    for (int r = 0; r < 4; r++)
                        if (key + r > qrow) st[kb][r] = -INFINITY;
                }
            }

            // tile max: max3 tree (depth ~4 instead of 16-deep chain)
            float x0 = fmaxf(fmaxf(st[0][0], st[0][1]), st[0][2]);
            float x1 = fmaxf(fmaxf(st[0][3], st[1][0]), st[1][1]);
            float x2 = fmaxf(fmaxf(st[1][2], st[1][3]), st[2][0]);
            float x3 = fmaxf(fmaxf(st[2][1], st[2][2]), st[2][3]);
            float x4 = fmaxf(fmaxf(st[3][0], st[3][1]), st[3][2]);
            float mt = fmaxf(fmaxf(fmaxf(x0, x1), fmaxf(x2, x3)),
                             fmaxf(x4, st[3][3]));
            mt = fmaxf(mt, __shfl_xor(mt, 16));
            mt = fmaxf(mt, __shfl_xor(mt, 32));

            // T13 defer-max: skip rescale while tile max stays within THR=8
            // (log2 domain -> P bounded by 2^8; bf16 headroom is fine).
            if (!__all(mt <= m_i + 8.0f)) {
                const float mn = fmaxf(m_i, mt);
                const float alpha = __builtin_amdgcn_exp2f(m_i - mn);
                m_i = mn;
                l_i *= alpha;
#pragma unroll
                for (int db = 0; db < 4; db++) {
                    o[db][0] *= alpha; o[db][1] *= alpha;
                    o[db][2] *= alpha; o[db][3] *= alpha;
                }
            }

            float r0, r1, r2, r3;
#pragma unroll
            for (int kb = 0; kb < 4; kb++) {
                const float e0 = __builtin_amdgcn_exp2f(st[kb][0] - m_i);
                const float e1 = __builtin_amdgcn_exp2f(st[kb][1] - m_i);
                const float e2 = __builtin_amdgcn_exp2f(st[kb][2] - m_i);
                const float e3 = __builtin_amdgcn_exp2f(st[kb][3] - m_i);
                st[kb][0] = e0; st[kb][1] = e1; st[kb][2] = e2; st[kb][3] = e3;
                const float rp = (e0 + e1) + (e2 + e3);
                if (kb == 0) r0 = rp; else if (kb == 1) r1 = rp;
                else if (kb == 2) r2 = rp; else r3 = rp;
            }
            float rs = (r0 + r1) + (r2 + r3);
            rs += __shfl_xor(rs, 16);
            rs += __shfl_xor(rs, 32);
            l_i += rs;

#pragma unroll
            for (int kb = 0; kb < 4; kb++) {
                u32x2 pk;
                pk[0] = f2bf_pack2(st[kb][0], st[kb][1]);
                pk[1] = f2bf_pack2(st[kb][2], st[kb][3]);
                *(u32x2*)&pw[lc * 72 + kb * 16 + quad * 4] = pk;
            }
            const s16x8 pb0 = *(const s16x8*)&pw[lc * 72 + quad * 8];
            const s16x8 pb1 = *(const s16x8*)&pw[lc * 72 + 32 + quad * 8];
            __builtin_amdgcn_s_setprio(1);
#pragma unroll
            for (int db = 0; db < 4; db++) {
                o[db] = __builtin_amdgcn_mfma_f32_16x16x32_bf16(va[db][0], pb0, o[db], 0, 0, 0);
                o[db] = __builtin_amdgcn_mfma_f32_16x16x32_bf16(va[db][1], pb1, o[db], 0, 0, 0);
            }
            __builtin_amdgcn_s_setprio(0);
        }

        {
            const float inv_l = 1.f / l_i;
            const int t = t0 + wave * 16 + lc;
            unsigned short* orow = out + (size_t)(b * T_SEQ + t) * DMODEL + h * HDIM + quad * 4;
#pragma unroll
            for (int db = 0; db < 4; db++) {
                u32x2 pk;
                pk[0] = f2bf_pack2(o[db][0] * inv_l, o[db][1] * inv_l);
                pk[1] = f2bf_pack2(o[db][2] * inv_l, o[db][3] * inv_l);
                *(u32x2*)(orow + db * 16) = pk;
            }
        }
    }
}

// ---------------------------------------------------------------------------
extern "C" void kernel_launch(void* const* d_in, const int* in_sizes, int n_in,
                              void* d_out, int out_size, void* d_ws, size_t ws_size,
                              hipStream_t stream)
{
    const float* x    = (const float*)d_in[0];   // (B,T,D) fp32
    const float* Wqkv = (const float*)d_in[1];   // (D,3D) fp32
    const float* Wout = (const float*)d_in[2];   // (D,D) fp32
    // d_in[3] attn_mask: causal triu(k=1), applied analytically.

    float* out = (float*)d_out;

    char* ws = (char*)d_ws;
    unsigned short* attnb  = (unsigned short*)(ws);               // (B,T,D) bf16, 8 MB
    unsigned short* Qb     = (unsigned short*)(ws + (8u  << 20)); // (B,H,T,64)
    unsigned short* Kb     = (unsigned short*)(ws + (16u << 20)); // (B,H,T,64)
    unsigned short* Vt     = (unsigned short*)(ws + (24u << 20)); // (B,H,64,T)
    unsigned short* xbuf   = (unsigned short*)(ws + (32u << 20)); // (M,K) bf16
    unsigned short* Wqkv_t = (unsigned short*)(ws + (40u << 20)); // (3D,D) bf16
    unsigned short* Wout_t = (unsigned short*)(ws + (46u << 20)); // (D,D) bf16
    float2*         ropeT  = (float2*)       (ws + (48u << 20)); // 2048x32 float2, 512 KB

    // 0) fused prep: convert x, transpose weights, build RoPE table
    prep_fused<<<dim3(3328), 256, 0, stream>>>(x, Wqkv, Wout, xbuf, Wqkv_t, Wout_t, ropeT);

    // 1) QKV GEMM, 256^2 8-phase pipeline + RoPE table + scale + pack
    gemm_qkv_rope_256<<<dim3(192), 512, 0, stream>>>(xbuf, Wqkv_t, ropeT, Qb, Kb, Vt);

    // 2) MFMA causal flash attention v8 -> attnb (B,T,D) bf16
    attn_mfma8<<<dim3(512), 256, 0, stream>>>(Qb, Kb, Vt, attnb);

    // 3) out = attnb @ Wout  (fp32 out, dbuf, XCD-affine)
    gemm_out_mfma<<<dim3(256), 256, 0, stream>>>(attnb, Wout_t, out, DMODEL, DMODEL);
}

// Round 3
// 195.379 us; speedup vs baseline: 1.0213x; 1.0006x over previous
//
#include <hip/hip_runtime.h>
#include <math.h>

#define BATCH   2
#define T_SEQ   2048
#define DMODEL  1024
#define NHEAD   16
#define HDIM    64

typedef short s16x8 __attribute__((ext_vector_type(8)));
typedef unsigned short u16x8 __attribute__((ext_vector_type(8)));
typedef unsigned short u16x4 __attribute__((ext_vector_type(4)));
typedef unsigned int u32x2 __attribute__((ext_vector_type(2)));
typedef float f32x4 __attribute__((ext_vector_type(4)));

typedef const unsigned int __attribute__((address_space(1))) GUI;
typedef unsigned int __attribute__((address_space(3))) LUI;

// fp32 -> bf16 round-to-nearest-even (bit pattern)
static __device__ __forceinline__ unsigned short f2bf(float f) {
    unsigned int u = __float_as_uint(f);
    u += 0x7fffu + ((u >> 16) & 1u);
    return (unsigned short)(u >> 16);
}

// two fp32 -> packed bf16x2 (round-half-up) via one v_perm_b32
static __device__ __forceinline__ unsigned int f2bf_pack2(float a, float b) {
    const unsigned int ua = __float_as_uint(a) + 0x8000u;
    const unsigned int ub = __float_as_uint(b) + 0x8000u;
    return __builtin_amdgcn_perm(ub, ua, 0x07060302u);
}

// ---------------------------------------------------------------------------
// Fused prep: blocks 0..2047 convert x -> bf16; 2048..2815 transpose Wqkv;
// 2816..3071 transpose Wout; 3072..3327 build RoPE cos/sin table
// ---------------------------------------------------------------------------
__global__ __launch_bounds__(256) void prep_fused(
    const float* __restrict__ x, const float* __restrict__ Wqkv,
    const float* __restrict__ Wout,
    unsigned short* __restrict__ xb, unsigned short* __restrict__ Wqkv_t,
    unsigned short* __restrict__ Wout_t, float2* __restrict__ rope_tab)
{
    __shared__ unsigned short tile[64][68];
    const int bid = blockIdx.x;
    const int tid = threadIdx.x;

    if (bid < 2048) {
        const int i = bid * 256 + tid;
        const float4 a = ((const float4*)x)[2 * i];
        const float4 b = ((const float4*)x)[2 * i + 1];
        u16x8 r;
        r[0] = f2bf(a.x); r[1] = f2bf(a.y); r[2] = f2bf(a.z); r[3] = f2bf(a.w);
        r[4] = f2bf(b.x); r[5] = f2bf(b.y); r[6] = f2bf(b.z); r[7] = f2bf(b.w);
        ((u16x8*)xb)[i] = r;
        return;
    }
    if (bid >= 3072) {
        const int idx = (bid - 3072) * 256 + tid;
        const int t = idx >> 5;
        const int d2 = idx & 31;
        const float inv_freq = exp2f(-(float)d2 * 0.41524101186092029f); // log2(1e4)/32
        float s, c;
        sincosf((float)t * inv_freq, &s, &c);
        rope_tab[idx] = make_float2(c, s);
        return;
    }

    const float* src;
    unsigned short* dst;
    int R, C, bx, by;
    if (bid < 2816) {
        const int id = bid - 2048;
        src = Wqkv; dst = Wqkv_t; R = DMODEL; C = 3 * DMODEL;
        bx = id % 48; by = id / 48;
    } else {
        const int id = bid - 2816;
        src = Wout; dst = Wout_t; R = DMODEL; C = DMODEL;
        bx = id % 16; by = id / 16;
    }
    const int tc0 = bx * 64;
    const int tr0 = by * 64;
    const int tx = tid & 63;
    const int ty = tid >> 6;
#pragma unroll
    for (int i = 0; i < 16; i++) {
        const int rr = i * 4 + ty;
        tile[tx][rr] = f2bf(src[(size_t)(tr0 + rr) * C + tc0 + tx]);
    }
    __syncthreads();
#pragma unroll
    for (int i = 0; i < 16; i++) {
        const int cc = i * 4 + ty;
        dst[(size_t)(tc0 + cc) * R + tr0 + tx] = tile[cc][tx];
    }
}

// ---------------------------------------------------------------------------
// Shared MFMA GEMM main loop, DOUBLE-BUFFERED, one barrier per K-slice.
// ---------------------------------------------------------------------------
__device__ __forceinline__ void mfma_gemm_loop_db(
    const unsigned short* __restrict__ A, const unsigned short* __restrict__ Bt,
    unsigned short* As, unsigned short* Bs,
    int m0, int n0, int K, f32x4 acc[4][4])
{
    const int tid  = threadIdx.x;
    const int wave = tid >> 6;
    const int lane = tid & 63;
    const int quad = lane >> 4;
    const int lc   = lane & 15;
    const int wr   = (wave >> 1) * 64;
    const int wc   = (wave & 1) * 64;

    const int c0    = wave * 2;
    const int srow0 = c0 * 16 + (lane >> 2);
    const int scol  = (lane & 3) * 8;

#pragma unroll
    for (int i = 0; i < 4; i++)
#pragma unroll
        for (int j = 0; j < 4; j++)
            acc[i][j] = (f32x4){0.f, 0.f, 0.f, 0.f};

    auto stage = [&](int kt, int buf) {
        const unsigned short* ga0 = A + (size_t)(m0 + srow0) * K + kt + scol;
        const unsigned short* ga1 = A + (size_t)(m0 + srow0 + 16) * K + kt + scol;
        const unsigned short* gb0 = Bt + (size_t)(n0 + srow0) * K + kt + scol;
        const unsigned short* gb1 = Bt + (size_t)(n0 + srow0 + 16) * K + kt + scol;
        unsigned short* as = As + buf * 4096;
        unsigned short* bs = Bs + buf * 4096;
        __builtin_amdgcn_global_load_lds((GUI*)ga0, (LUI*)(as + c0 * 512 + lane * 8), 16, 0, 0);
        __builtin_amdgcn_global_load_lds((GUI*)ga1, (LUI*)(as + (c0 + 1) * 512 + lane * 8), 16, 0, 0);
        __builtin_amdgcn_global_load_lds((GUI*)gb0, (LUI*)(bs + c0 * 512 + lane * 8), 16, 0, 0);
        __builtin_amdgcn_global_load_lds((GUI*)gb1, (LUI*)(bs + (c0 + 1) * 512 + lane * 8), 16, 0, 0);
    };

    stage(0, 0);
    const int nit = K >> 5;
    for (int it = 0; it < nit; ++it) {
        __syncthreads();
        if (it + 1 < nit) stage((it + 1) << 5, (it + 1) & 1);

        const unsigned short* as = As + (it & 1) * 4096;
        const unsigned short* bs = Bs + (it & 1) * 4096;
        s16x8 a[4], b[4];
#pragma unroll
        for (int mt = 0; mt < 4; mt++)
            a[mt] = *(const s16x8*)(as + (wr + mt * 16 + lc) * 32 + quad * 8);
#pragma unroll
        for (int nb = 0; nb < 4; nb++)
            b[nb] = *(const s16x8*)(bs + (wc + nb * 16 + lc) * 32 + quad * 8);
#pragma unroll
        for (int mt = 0; mt < 4; mt++)
#pragma unroll
            for (int nb = 0; nb < 4; nb++)
                acc[mt][nb] = __builtin_amdgcn_mfma_f32_16x16x32_bf16(a[mt], b[nb], acc[mt][nb], 0, 0, 0);
    }
}

// ---------------------------------------------------------------------------
// QKV GEMM (bf16 MFMA, dbuf) + RoPE (table lookup) + Q-scale + pack.
// 1-D grid 768, XCD-affine. (Round-0 proven version: 49.8 us. The 256^2
// 8-phase port lost its A/B twice — reverted.)
// ---------------------------------------------------------------------------
__global__ __launch_bounds__(256) void gemm_qkv_rope_mfma(
    const unsigned short* __restrict__ xb, const unsigned short* __restrict__ Wt,
    const float2* __restrict__ rope_tab,
    unsigned short* __restrict__ Qb, unsigned short* __restrict__ Kb,
    unsigned short* __restrict__ Vb)
{
    __shared__ __align__(16) unsigned short As[2 * 128 * 32];
    __shared__ __align__(16) unsigned short Bs[2 * 128 * 32];

    const int id  = blockIdx.x;               // 0..767
    const int s   = id >> 3;                  // 0..95
    const int n0  = ((id & 7) * 3 + (s % 3)) * 128;
    const int m0  = (s / 3) * 128;
    f32x4 acc[4][4];
    mfma_gemm_loop_db(xb, Wt, As, Bs, m0, n0, DMODEL, acc);

    const int lane = threadIdx.x & 63;
    const int wave = threadIdx.x >> 6;
    const int quad = lane >> 4;
    const int lc   = lane & 15;
    const int wr   = (wave >> 1) * 64;
    const int wc   = (wave & 1) * 64;

    const int n_base = n0 + wc;
    const int part = n_base >> 10;       // 0=q 1=k 2=v, uniform per block
    unsigned short* dst = (part == 0) ? Qb : (part == 1 ? Kb : Vb);
    const float scale = (part == 0) ? 0.125f * 1.4426950408889634f : 1.0f;

#pragma unroll
    for (int nb = 0; nb < 4; nb++) {
        const int n = n_base + nb * 16 + lc;
        const int h = (n >> 6) & 15;
        const int d = n & 63;
        if (part == 2) {
#pragma unroll
            for (int mt = 0; mt < 4; mt++) {
                const int mb = m0 + wr + mt * 16 + quad * 4;
                const int bb = mb >> 11, t = mb & 2047;
                u16x4 pk;
                pk[0] = f2bf(acc[mt][nb][0]); pk[1] = f2bf(acc[mt][nb][1]);
                pk[2] = f2bf(acc[mt][nb][2]); pk[3] = f2bf(acc[mt][nb][3]);
                *(u16x4*)&dst[((size_t)(bb * NHEAD + h) * HDIM + d) * T_SEQ + t] = pk;
            }
        } else {
            const size_t hb = (size_t)h * T_SEQ * HDIM + d;
            const int d2 = d >> 1;
            const float ssign = (lc & 1) ? 1.f : -1.f;
#pragma unroll
            for (int mt = 0; mt < 4; mt++) {
                const int mb = m0 + wr + mt * 16 + quad * 4;
#pragma unroll
                for (int r = 0; r < 4; r++) {
                    const float val = acc[mt][nb][r];
                    const float prt = __shfl_xor(val, 1);
                    const int m = mb + r;
                    const int bb = m >> 11, t = m & 2047;
                    const float2 sc = rope_tab[t * 32 + d2];   // (cos, sin)
                    const float res = fmaf(prt, ssign * sc.y, val * sc.x) * scale;
                    dst[(size_t)bb * NHEAD * T_SEQ * HDIM + hb + (size_t)t * HDIM] = f2bf(res);
                }
            }
        }
    }
}

// ---------------------------------------------------------------------------
// Out-proj GEMM (bf16 MFMA, dbuf): out[M,1024] fp32 = attnb x Wout_t^T.
// ---------------------------------------------------------------------------
__global__ __launch_bounds__(256) void gemm_out_mfma(
    const unsigned short* __restrict__ A, const unsigned short* __restrict__ Bt,
    float* __restrict__ C, int N, int K)
{
    __shared__ __align__(16) unsigned short As[2 * 128 * 32];
    __shared__ __align__(16) unsigned short Bs[2 * 128 * 32];

    const int id = blockIdx.x;            // 0..255
    const int n0 = (id & 7) * 128;
    const int m0 = (id >> 3) * 128;
    f32x4 acc[4][4];
    mfma_gemm_loop_db(A, Bt, As, Bs, m0, n0, K, acc);

    const int lane = threadIdx.x & 63;
    const int wave = threadIdx.x >> 6;
    const int quad = lane >> 4;
    const int lc   = lane & 15;
    const int wr   = (wave >> 1) * 64;
    const int wc   = (wave & 1) * 64;

#pragma unroll
    for (int mt = 0; mt < 4; mt++) {
        const int mb = m0 + wr + mt * 16 + quad * 4;
#pragma unroll
        for (int r = 0; r < 4; r++) {
            float* row = C + (size_t)(mb + r) * N + n0 + wc;
#pragma unroll
            for (int nb = 0; nb < 4; nb++)
                row[nb * 16 + lc] = acc[mt][nb][r];
        }
    }
}

// ---------------------------------------------------------------------------
// MFMA causal flash attention v8: v7 + T13 defer-max (THR=8 in log2 domain),
// T5 setprio around MFMA clusters, tree-shaped max/sum reductions.
// ---------------------------------------------------------------------------
__global__ __launch_bounds__(256, 2) void attn_mfma8(
    const unsigned short* __restrict__ Qb, const unsigned short* __restrict__ Kb,
    const unsigned short* __restrict__ Vtg, unsigned short* __restrict__ out)
{
    __shared__ __align__(16) unsigned short Ks[2][64 * 64];
    __shared__ __align__(16) unsigned short Vs[2][64 * 64];
    __shared__ __align__(16) unsigned short Ps[4][16 * 72];

    const int tid  = threadIdx.x;
    const int lane = tid & 63;
    const int wave = tid >> 6;           // 0..3
    const int quad = lane >> 4;
    const int lc   = lane & 15;
    const int rsw  = lc & 7;

    const int id   = blockIdx.x;             // 0..511
    const int slot = id >> 3;                // 0..63
    const int bh   = (id & 7) + 8 * (slot & 3);   // 4 heads per XCD
    const int xb   = slot >> 2;              // 0..15

    const size_t headK = (size_t)bh * T_SEQ * HDIM;   // Q,K: (BH,T,64)
    const size_t headV = (size_t)bh * HDIM * T_SEQ;   // Vt:  (BH,64,T)
    const int b = bh >> 4;
    const int h = bh & 15;

    const int c0   = wave * 2;
    const int krow = lane >> 3;
    const int d8sw = (lane & 7) ^ krow;
    unsigned short* pw = Ps[wave];

#pragma unroll
    for (int pass = 0; pass < 2; pass++) {
        const int qb = pass ? (31 - xb) : xb;
        const int t0 = qb * 64;
        const int n_tiles = qb + 1;

        s16x8 qf0, qf1;
        {
            const size_t qrow = headK + (size_t)(t0 + wave * 16 + lc) * HDIM;
            qf0 = *(const s16x8*)(Qb + qrow + quad * 8);
            qf1 = *(const s16x8*)(Qb + qrow + 32 + quad * 8);
        }

        f32x4 o[4];
        float m_i = -INFINITY, l_i = 0.f;
#pragma unroll
        for (int db = 0; db < 4; db++)
            o[db] = (f32x4){0.f, 0.f, 0.f, 0.f};

        auto stage = [&](int s0, int buf) {
            const unsigned short* gk0 = Kb  + headK + (size_t)(s0 + c0 * 8 + krow) * HDIM + d8sw * 8;
            const unsigned short* gk1 = Kb  + headK + (size_t)(s0 + c0 * 8 + 8 + krow) * HDIM + d8sw * 8;
            const unsigned short* gv0 = Vtg + headV + (size_t)(c0 * 8 + krow) * T_SEQ + s0 + d8sw * 8;
            const unsigned short* gv1 = Vtg + headV + (size_t)(c0 * 8 + 8 + krow) * T_SEQ + s0 + d8sw * 8;
            __builtin_amdgcn_global_load_lds((GUI*)gk0, (LUI*)(Ks[buf] + c0 * 512 + lane * 8), 16, 0, 0);
            __builtin_amdgcn_global_load_lds((GUI*)gk1, (LUI*)(Ks[buf] + (c0 + 1) * 512 + lane * 8), 16, 0, 0);
            __builtin_amdgcn_global_load_lds((GUI*)gv0, (LUI*)(Vs[buf] + c0 * 512 + lane * 8), 16, 0, 0);
            __builtin_amdgcn_global_load_lds((GUI*)gv1, (LUI*)(Vs[buf] + (c0 + 1) * 512 + lane * 8), 16, 0, 0);
        };

        __syncthreads();
        stage(0, 0);

        for (int tile = 0; tile < n_tiles; ++tile) {
            const int s0 = tile * 64;
            const int buf = tile & 1;
            __syncthreads();
            if (tile + 1 < n_tiles) stage(s0 + 64, buf ^ 1);

            const unsigned short* ks = Ks[buf];
            const unsigned short* vs = Vs[buf];

            f32x4 st[4];
            __builtin_amdgcn_s_setprio(1);
#pragma unroll
            for (int kb = 0; kb < 4; kb++) {
                const s16x8 ka0 = *(const s16x8*)&ks[(kb * 16 + lc) * 64 + ((quad ^ rsw) * 8)];
                const s16x8 ka1 = *(const s16x8*)&ks[(kb * 16 + lc) * 64 + (((4 + quad) ^ rsw) * 8)];
                f32x4 z = (f32x4){0.f, 0.f, 0.f, 0.f};
                z = __builtin_amdgcn_mfma_f32_16x16x32_bf16(ka0, qf0, z, 0, 0, 0);
                z = __builtin_amdgcn_mfma_f32_16x16x32_bf16(ka1, qf1, z, 0, 0, 0);
                st[kb] = z;
            }
            __builtin_amdgcn_s_setprio(0);

            s16x8 va[4][2];
#pragma unroll
            for (int db = 0; db < 4; db++) {
                va[db][0] = *(const s16x8*)&vs[(db * 16 + lc) * 64 + ((quad ^ rsw) * 8)];
                va[db][1] = *(const s16x8*)&vs[(db * 16 + lc) * 64 + (((4 + quad) ^ rsw) * 8)];
            }

            if (tile == n_tiles - 1) {
                const int qrow = t0 + wave * 16 + lc;
#pragma unroll
                for (int kb = 0; kb < 4; kb++) {
                    const int key = s0 + kb * 16 + quad * 4;
#pragma unroll
                    for (int r = 0; r < 4; r++)
                        if (key + r > qrow) st[kb][r] = -INFINITY;
                }
            }

            // tile max: tree reduction (depth ~4 instead of 16-deep chain)
            float x0 = fmaxf(fmaxf(st[0][0], st[0][1]), st[0][2]);
            float x1 = fmaxf(fmaxf(st[0][3], st[1][0]), st[1][1]);
            float x2 = fmaxf(fmaxf(st[1][2], st[1][3]), st[2][0]);
            float x3 = fmaxf(fmaxf(st[2][1], st[2][2]), st[2][3]);
            float x4 = fmaxf(fmaxf(st[3][0], st[3][1]), st[3][2]);
            float mt = fmaxf(fmaxf(fmaxf(x0, x1), fmaxf(x2, x3)),
                             fmaxf(x4, st[3][3]));
            mt = fmaxf(mt, __shfl_xor(mt, 16));
            mt = fmaxf(mt, __shfl_xor(mt, 32));

            // T13 defer-max: skip rescale while tile max stays within THR=8
            // (log2 domain -> P bounded by 2^8; f32 accum headroom fine).
            if (!__all(mt <= m_i + 8.0f)) {
                const float mn = fmaxf(m_i, mt);
                const float alpha = __builtin_amdgcn_exp2f(m_i - mn);
                m_i = mn;
                l_i *= alpha;
#pragma unroll
                for (int db = 0; db < 4; db++) {
                    o[db][0] *= alpha; o[db][1] *= alpha;
                    o[db][2] *= alpha; o[db][3] *= alpha;
                }
            }

            float r0, r1, r2, r3;
#pragma unroll
            for (int kb = 0; kb < 4; kb++) {
                const float e0 = __builtin_amdgcn_exp2f(st[kb][0] - m_i);
                const float e1 = __builtin_amdgcn_exp2f(st[kb][1] - m_i);
                const float e2 = __builtin_amdgcn_exp2f(st[kb][2] - m_i);
                const float e3 = __builtin_amdgcn_exp2f(st[kb][3] - m_i);
                st[kb][0] = e0; st[kb][1] = e1; st[kb][2] = e2; st[kb][3] = e3;
                const float rp = (e0 + e1) + (e2 + e3);
                if (kb == 0) r0 = rp; else if (kb == 1) r1 = rp;
                else if (kb == 2) r2 = rp; else r3 = rp;
            }
            float rs = (r0 + r1) + (r2 + r3);
            rs += __shfl_xor(rs, 16);
            rs += __shfl_xor(rs, 32);
            l_i += rs;

#pragma unroll
            for (int kb = 0; kb < 4; kb++) {
                u32x2 pk;
                pk[0] = f2bf_pack2(st[kb][0], st[kb][1]);
                pk[1] = f2bf_pack2(st[kb][2], st[kb][3]);
                *(u32x2*)&pw[lc * 72 + kb * 16 + quad * 4] = pk;
            }
            const s16x8 pb0 = *(const s16x8*)&pw[lc * 72 + quad * 8];
            const s16x8 pb1 = *(const s16x8*)&pw[lc * 72 + 32 + quad * 8];
            __builtin_amdgcn_s_setprio(1);
#pragma unroll
            for (int db = 0; db < 4; db++) {
                o[db] = __builtin_amdgcn_mfma_f32_16x16x32_bf16(va[db][0], pb0, o[db], 0, 0, 0);
                o[db] = __builtin_amdgcn_mfma_f32_16x16x32_bf16(va[db][1], pb1, o[db], 0, 0, 0);
            }
            __builtin_amdgcn_s_setprio(0);
        }

        {
            const float inv_l = 1.f / l_i;
            const int t = t0 + wave * 16 + lc;
            unsigned short* orow = out + (size_t)(b * T_SEQ + t) * DMODEL + h * HDIM + quad * 4;
#pragma unroll
            for (int db = 0; db < 4; db++) {
                u32x2 pk;
                pk[0] = f2bf_pack2(o[db][0] * inv_l, o[db][1] * inv_l);
                pk[1] = f2bf_pack2(o[db][2] * inv_l, o[db][3] * inv_l);
                *(u32x2*)(orow + db * 16) = pk;
            }
        }
    }
}

// ---------------------------------------------------------------------------
extern "C" void kernel_launch(void* const* d_in, const int* in_sizes, int n_in,
                              void* d_out, int out_size, void* d_ws, size_t ws_size,
                              hipStream_t stream)
{
    const float* x    = (const float*)d_in[0];   // (B,T,D) fp32
    const float* Wqkv = (const float*)d_in[1];   // (D,3D) fp32
    const float* Wout = (const float*)d_in[2];   // (D,D) fp32
    // d_in[3] attn_mask: causal triu(k=1), applied analytically.

    float* out = (float*)d_out;

    char* ws = (char*)d_ws;
    unsigned short* attnb  = (unsigned short*)(ws);               // (B,T,D) bf16, 8 MB
    unsigned short* Qb     = (unsigned short*)(ws + (8u  << 20)); // (B,H,T,64)
    unsigned short* Kb     = (unsigned short*)(ws + (16u << 20)); // (B,H,T,64)
    unsigned short* Vt     = (unsigned short*)(ws + (24u << 20)); // (B,H,64,T)
    unsigned short* xbuf   = (unsigned short*)(ws + (32u << 20)); // (M,K) bf16
    unsigned short* Wqkv_t = (unsigned short*)(ws + (40u << 20)); // (3D,D) bf16
    unsigned short* Wout_t = (unsigned short*)(ws + (46u << 20)); // (D,D) bf16
    float2*         ropeT  = (float2*)       (ws + (48u << 20)); // 2048x32 float2, 512 KB

    // 0) fused prep: convert x, transpose weights, build RoPE table
    prep_fused<<<dim3(3328), 256, 0, stream>>>(x, Wqkv, Wout, xbuf, Wqkv_t, Wout_t, ropeT);

    // 1) QKV MFMA GEMM (dbuf, XCD-affine) + RoPE table + scale + pack
    gemm_qkv_rope_mfma<<<dim3(768), 256, 0, stream>>>(xbuf, Wqkv_t, ropeT, Qb, Kb, Vt);

    // 2) MFMA causal flash attention v8 -> attnb (B,T,D) bf16
    attn_mfma8<<<dim3(512), 256, 0, stream>>>(Qb, Kb, Vt, attnb);

    // 3) out = attnb @ Wout  (fp32 out, dbuf, XCD-affine)
    gemm_out_mfma<<<dim3(256), 256, 0, stream>>>(attnb, Wout_t, out, DMODEL, DMODEL);
}